// Round 5
// baseline (133.811 us; speedup 1.0000x reference)
//
#include <hip/hip_runtime.h>
#include <stdint.h>

#define BB 8
#define NN 2048
#define EE 2048
#define DD 128
#define ROWS 32
#define RBP 132     // rowbuf pitch (floats)
#define HTP 36      // hT pitch (floats)
#define NTHREADS 256

// packed bf16-pair weight matrices: 6 mats x 8192 u32 (32 KB each)
#define WPK_U32 8192

__device__ inline unsigned bf16rne(float f) {
    unsigned u = __float_as_uint(f);
    return (u + 0x7fffu + ((u >> 16) & 1u)) >> 16;
}

struct Smem {
    float rowbuf[ROWS][RBP];   // compacted row state
    float hT[DD][HTP];         // transposed activations, permuted cols pcol=(ci&3)*8+(ci>>2)
    unsigned wlds[DD * 64];    // 32 KB: packed bf16 W pairs, wlds[k*64 + jpair]
    int actlist[ROWS];
    int invmap[ROWS];
    int ords[ROWS];
    int mcount;
};

// ---- prologue: pack 6 weight matrices fp32 -> bf16 pairs ----
__global__ __launch_bounds__(NTHREADS) void convert_w_kernel(
    const float* __restrict__ W11, const float* __restrict__ W12,
    const float* __restrict__ W21, const float* __restrict__ W22,
    const float* __restrict__ W31, const float* __restrict__ W32,
    unsigned* __restrict__ Wpk) {
    int tid = blockIdx.x * NTHREADS + threadIdx.x;
    if (tid >= 6 * WPK_U32) return;
    int mat = tid >> 13;
    int off = tid & (WPK_U32 - 1);
    const float* src = mat == 0 ? W11 : mat == 1 ? W12 : mat == 2 ? W21
                     : mat == 3 ? W22 : mat == 4 ? W31 : W32;
    float w0 = src[2 * off], w1 = src[2 * off + 1];
    Wpk[tid] = bf16rne(w0) | (bf16rne(w1) << 16);
}

// ---- build compacted active-row list from mask (int32 0/1) ----
__device__ inline int block_compact(Smem& s, const int* __restrict__ mask, int row0,
                                    const int* __restrict__ orders) {
    int t = threadIdx.x;
    if (t < 64) {
        bool act = (t < ROWS) && (mask[row0 + t] != 0);
        unsigned long long bal = __ballot(act);
        if (t < ROWS) {
            int pos = __popcll(bal & ((1ull << t) - 1ull));
            if (act) {
                s.actlist[pos] = t;
                if (orders) {
                    int o = orders[row0 + t];
                    o = o < 0 ? 0 : (o > 8 ? 8 : o);
                    s.ords[pos] = o;
                }
            }
            s.invmap[t] = act ? pos : -1;
            if (t == 0) s.mcount = __popcll(bal);
        }
    }
    __syncthreads();
    return s.mcount;
}

__device__ inline void block_load_rows(Smem& s, int m, const float* __restrict__ src) {
    int t = threadIdx.x;
    int total4 = m * (DD / 4);
    for (int idx = t; idx < total4; idx += NTHREADS) {
        int ci = idx >> 5;
        int c4 = (idx & 31) * 4;
        int orig = s.actlist[ci];
        float4 v = *(const float4*)&src[orig * DD + c4];
        *(float4*)&s.rowbuf[ci][c4] = v;
    }
    __syncthreads();
}

// ---- stage one packed W matrix (32 KB) into LDS; NO trailing barrier ----
__device__ inline void stage_w(Smem& s, const unsigned* __restrict__ src) {
    int t = threadIdx.x;
    const uint4* s4 = (const uint4*)src;
    uint4* d4 = (uint4*)s.wlds;
    #pragma unroll
    for (int i = 0; i < 8; i++) d4[t + 256 * i] = s4[t + 256 * i];
}

// ---- LayerNorm rowbuf -> hT (permuted cols), optional PE; trailing barrier ----
__device__ inline void block_ln(Smem& s, int m,
                                const float* __restrict__ gw, const float* __restrict__ bw,
                                const float* __restrict__ pe_base, const int* __restrict__ ords) {
    int t = threadIdx.x;
    int gr = t >> 3, g = t & 7;
    int base = g * 16;
    float4 xv0 = *(const float4*)&s.rowbuf[gr][base + 0];
    float4 xv1 = *(const float4*)&s.rowbuf[gr][base + 4];
    float4 xv2 = *(const float4*)&s.rowbuf[gr][base + 8];
    float4 xv3 = *(const float4*)&s.rowbuf[gr][base + 12];
    float s1 = 0.f, s2 = 0.f;
    {
        float v;
        v = xv0.x; s1 += v; s2 += v * v;  v = xv0.y; s1 += v; s2 += v * v;
        v = xv0.z; s1 += v; s2 += v * v;  v = xv0.w; s1 += v; s2 += v * v;
        v = xv1.x; s1 += v; s2 += v * v;  v = xv1.y; s1 += v; s2 += v * v;
        v = xv1.z; s1 += v; s2 += v * v;  v = xv1.w; s1 += v; s2 += v * v;
        v = xv2.x; s1 += v; s2 += v * v;  v = xv2.y; s1 += v; s2 += v * v;
        v = xv2.z; s1 += v; s2 += v * v;  v = xv2.w; s1 += v; s2 += v * v;
        v = xv3.x; s1 += v; s2 += v * v;  v = xv3.y; s1 += v; s2 += v * v;
        v = xv3.z; s1 += v; s2 += v * v;  v = xv3.w; s1 += v; s2 += v * v;
    }
    #pragma unroll
    for (int off = 1; off < 8; off <<= 1) {
        s1 += __shfl_xor(s1, off, 64);
        s2 += __shfl_xor(s2, off, 64);
    }
    float mu = s1 * (1.f / 128.f);
    float var = s2 * (1.f / 128.f) - mu * mu;
    float rstd = rsqrtf(var + 1e-5f);
    if (gr < m) {
        int pcol = ((gr & 3) << 3) | (gr >> 2);
        const float* pe = nullptr;
        if (pe_base) pe = ords ? (pe_base + (size_t)ords[gr] * DD) : pe_base;
        float xr[16] = {xv0.x, xv0.y, xv0.z, xv0.w, xv1.x, xv1.y, xv1.z, xv1.w,
                        xv2.x, xv2.y, xv2.z, xv2.w, xv3.x, xv3.y, xv3.z, xv3.w};
        #pragma unroll
        for (int i = 0; i < 16; i++) {
            int k = base + i;
            float v = (xr[i] - mu) * rstd * gw[k] + bw[k];
            if (pe) v += pe[k];
            s.hT[k][pcol] = v;
        }
    }
    __syncthreads();
}

// ---- matmul from LDS weights: wave w owns pcols [8w,8w+8) == rows w+4r ----
template <bool TO_HIDDEN>
__device__ inline void block_mm(Smem& s, int m, const float* __restrict__ bias) {
    int t = threadIdx.x;
    int w = t >> 6, l = t & 63;
    int pc0 = w * 8;
    int rm = (m > w) ? ((m - w + 3) >> 2) : 0;
    float acc[8][2];
    #pragma unroll
    for (int r = 0; r < 8; r++) { acc[r][0] = 0.f; acc[r][1] = 0.f; }
    if (rm > 4) {
        #pragma unroll 4
        for (int k = 0; k < DD; k++) {
            unsigned u = s.wlds[(k << 6) + l];
            float wx = __uint_as_float(u << 16);
            float wy = __uint_as_float(u & 0xffff0000u);
            float4 ha = *(const float4*)&s.hT[k][pc0];
            float4 hb = *(const float4*)&s.hT[k][pc0 + 4];
            acc[0][0] += ha.x * wx; acc[0][1] += ha.x * wy;
            acc[1][0] += ha.y * wx; acc[1][1] += ha.y * wy;
            acc[2][0] += ha.z * wx; acc[2][1] += ha.z * wy;
            acc[3][0] += ha.w * wx; acc[3][1] += ha.w * wy;
            acc[4][0] += hb.x * wx; acc[4][1] += hb.x * wy;
            acc[5][0] += hb.y * wx; acc[5][1] += hb.y * wy;
            acc[6][0] += hb.z * wx; acc[6][1] += hb.z * wy;
            acc[7][0] += hb.w * wx; acc[7][1] += hb.w * wy;
        }
    } else if (rm > 0) {
        #pragma unroll 4
        for (int k = 0; k < DD; k++) {
            unsigned u = s.wlds[(k << 6) + l];
            float wx = __uint_as_float(u << 16);
            float wy = __uint_as_float(u & 0xffff0000u);
            float4 ha = *(const float4*)&s.hT[k][pc0];
            acc[0][0] += ha.x * wx; acc[0][1] += ha.x * wy;
            acc[1][0] += ha.y * wx; acc[1][1] += ha.y * wy;
            acc[2][0] += ha.z * wx; acc[2][1] += ha.z * wy;
            acc[3][0] += ha.w * wx; acc[3][1] += ha.w * wy;
        }
    }
    float2 bv = *(const float2*)&bias[2 * l];
    __syncthreads();   // all hT/wlds reads done before overwrite
    #pragma unroll
    for (int r = 0; r < 8; r++) {
        if (r < rm) {
            if (TO_HIDDEN) {
                s.hT[2 * l][pc0 + r]     = fmaxf(acc[r][0] + bv.x, 0.f);
                s.hT[2 * l + 1][pc0 + r] = fmaxf(acc[r][1] + bv.y, 0.f);
            } else {
                int ci = w + 4 * r;
                float2* rb = (float2*)&s.rowbuf[ci][2 * l];
                float2 cur = *rb;
                cur.x += acc[r][0] + bv.x;
                cur.y += acc[r][1] + bv.y;
                *rb = cur;
            }
        }
    }
    __syncthreads();
}

// ---- write all ROWS rows (masked -> 0), optional bias add ----
__device__ inline void block_store_out(Smem& s, float* __restrict__ dst,
                                       const float* __restrict__ bias) {
    int t = threadIdx.x;
    for (int idx = t; idx < ROWS * (DD / 4); idx += NTHREADS) {
        int r = idx >> 5;
        int c4 = (idx & 31) * 4;
        int ci = s.invmap[r];
        float4 v = make_float4(0.f, 0.f, 0.f, 0.f);
        if (ci >= 0) {
            v = *(const float4*)&s.rowbuf[ci][c4];
            if (bias) {
                float4 bb = *(const float4*)&bias[c4];
                v.x += bb.x; v.y += bb.y; v.z += bb.z; v.w += bb.w;
            }
        }
        *(float4*)&dst[r * DD + c4] = v;
    }
}

// ---- kernel 1: MLP1 on edges (blocks [0,512)) and nodes ([512,1024)) ----
__global__ __launch_bounds__(NTHREADS) void stage1_kernel(
    const float* __restrict__ x_e, const float* __restrict__ x_v,
    const int* __restrict__ emask, const int* __restrict__ nmask,
    const int* __restrict__ eord, const float* __restrict__ pe1,
    const float* __restrict__ n1g, const float* __restrict__ n1b,
    const unsigned* __restrict__ Wpk,
    const float* __restrict__ b1, const float* __restrict__ b2,
    float* __restrict__ e2, float* __restrict__ v2) {
    __shared__ Smem s;
    int bid = blockIdx.x;
    const int EB = BB * EE / ROWS;
    bool isEdge = bid < EB;
    int lb = isEdge ? bid : bid - EB;
    int b = lb / (EE / ROWS);
    int r0 = (lb % (EE / ROWS)) * ROWS;
    int rowbase = b * EE + r0;
    const int* mask = isEdge ? emask : nmask;
    const float* src = isEdge ? x_e : x_v;
    float* dst = isEdge ? e2 : v2;
    int m = block_compact(s, mask, rowbase, isEdge ? eord : nullptr);
    if (m > 0) {
        block_load_rows(s, m, src + (size_t)rowbase * DD);
        stage_w(s, Wpk + 0 * WPK_U32);                     // W11
        block_ln(s, m, n1g, n1b, isEdge ? pe1 : (pe1 + DD), isEdge ? s.ords : nullptr);
        block_mm<true>(s, m, b1);
        stage_w(s, Wpk + 1 * WPK_U32);                     // W12
        __syncthreads();
        block_mm<false>(s, m, b2);
    }
    block_store_out(s, dst + (size_t)rowbase * DD, nullptr);
}

// ---- kernel 2: fused scan+gather, one wave per node row, NO barriers ----
__global__ __launch_bounds__(NTHREADS) void gather_kernel(
    float* __restrict__ v2out, const int* __restrict__ nmask,
    const float* __restrict__ inc, const float* __restrict__ sn,
    const float* __restrict__ e2) {
    __shared__ unsigned scratch[NTHREADS / 64][64];
    int wib = threadIdx.x >> 6, l = threadIdx.x & 63;
    int row = blockIdx.x * (NTHREADS / 64) + wib;
    if (row >= BB * NN) return;
    if (nmask[row] == 0) return;       // masked: left zero by stage1, overwritten by node2
    unsigned long long lmlt = (1ull << l) - 1ull;
    const float4* ir = (const float4*)(inc + (size_t)row * EE);
    float4 v[8];
    #pragma unroll
    for (int i = 0; i < 8; i++) v[i] = ir[l + 64 * i];     // 8 KB/wave in flight
    unsigned* sc = scratch[wib];
    int total = 0;
    #pragma unroll
    for (int i = 0; i < 8; i++) {
        #pragma unroll
        for (int c = 0; c < 4; c++) {
            float val = (c == 0) ? v[i].x : (c == 1) ? v[i].y : (c == 2) ? v[i].z : v[i].w;
            bool nz = (val != 0.f);
            unsigned long long msk = __ballot(nz);
            if (nz) {
                int pos = total + __popcll(msk & lmlt);
                if (pos < 64) {
                    unsigned e = (unsigned)((l + 64 * i) * 4 + c);
                    sc[pos] = (e << 16) | bf16rne(val);
                }
            }
            total += __popcll(msk);
        }
    }
    if (total > 64) total = 64;
    asm volatile("s_waitcnt lgkmcnt(0)" ::: "memory");     // wave-local LDS ordering
    unsigned pk = (l < total) ? sc[l] : 0u;
    const float* e2_b = e2 + ((size_t)(row >> 11)) * EE * DD;   // row>>11 == batch
    float2 cur = *(const float2*)&v2out[(size_t)row * DD + 2 * l];
    float ax = 0.f, ay = 0.f;
    for (int j0 = 0; j0 < total; j0 += 8) {
        int nn = total - j0;
        float2 r[8]; float wg[8];
        #pragma unroll
        for (int u = 0; u < 8; u++) {
            unsigned p = __shfl(pk, j0 + u, 64);
            if (u < nn) {
                r[u] = *(const float2*)&e2_b[(size_t)(p >> 16) * DD + 2 * l];
                wg[u] = __uint_as_float(p << 16);
            } else {
                r[u] = make_float2(0.f, 0.f); wg[u] = 0.f;
            }
        }
        #pragma unroll
        for (int u = 0; u < 8; u++) { ax += wg[u] * r[u].x; ay += wg[u] * r[u].y; }
    }
    float inv = 1.f / (1.f + sn[row]);
    cur.x += ax * inv;
    cur.y += ay * inv;
    *(float2*)&v2out[(size_t)row * DD + 2 * l] = cur;      // x1 in place
}

// ---- kernel 3: MLP2 + MLP3 on nodes ----
__global__ __launch_bounds__(NTHREADS) void node2_kernel(
    const float* __restrict__ x1, const int* __restrict__ nmask,
    const float* __restrict__ pe2, const float* __restrict__ biasb,
    const float* __restrict__ n2g, const float* __restrict__ n2b,
    const float* __restrict__ n3g, const float* __restrict__ n3b,
    const unsigned* __restrict__ Wpk,
    const float* __restrict__ b21, const float* __restrict__ b22,
    const float* __restrict__ b31, const float* __restrict__ b32,
    float* __restrict__ out) {
    __shared__ Smem s;
    int bid = blockIdx.x;
    int b = bid / (NN / ROWS);
    int n0 = (bid % (NN / ROWS)) * ROWS;
    int rowbase = b * NN + n0;
    int m = block_compact(s, nmask, rowbase, nullptr);
    if (m == 0) return;                                    // rows stay zero
    block_load_rows(s, m, x1 + (size_t)rowbase * DD);
    stage_w(s, Wpk + 2 * WPK_U32);                         // W21
    block_ln(s, m, n2g, n2b, pe2 + DD, nullptr);
    block_mm<true>(s, m, b21);
    stage_w(s, Wpk + 3 * WPK_U32);                         // W22
    __syncthreads();
    block_mm<false>(s, m, b22);
    stage_w(s, Wpk + 4 * WPK_U32);                         // W31
    block_ln(s, m, n3g, n3b, nullptr, nullptr);
    block_mm<true>(s, m, b31);
    stage_w(s, Wpk + 5 * WPK_U32);                         // W32
    __syncthreads();
    block_mm<false>(s, m, b32);
    block_store_out(s, out + (size_t)rowbase * DD, biasb);
}

extern "C" void kernel_launch(void* const* d_in, const int* in_sizes, int n_in,
                              void* d_out, int out_size, void* d_ws, size_t ws_size,
                              hipStream_t stream) {
    const float* x_v   = (const float*)d_in[0];
    const float* x_e   = (const float*)d_in[1];
    const float* inc   = (const float*)d_in[2];
    const float* sn    = (const float*)d_in[3];
    const int*   eord  = (const int*)d_in[4];
    const int*   nmask = (const int*)d_in[5];
    const int*   emask = (const int*)d_in[6];
    const float* pe1   = (const float*)d_in[7];
    const float* pe2   = (const float*)d_in[8];
    const float* biasb = (const float*)d_in[9];
    const float* W11   = (const float*)d_in[10];
    const float* b11   = (const float*)d_in[11];
    const float* W12   = (const float*)d_in[12];
    const float* b12   = (const float*)d_in[13];
    const float* W21   = (const float*)d_in[14];
    const float* b21   = (const float*)d_in[15];
    const float* W22   = (const float*)d_in[16];
    const float* b22   = (const float*)d_in[17];
    const float* W31   = (const float*)d_in[18];
    const float* b31   = (const float*)d_in[19];
    const float* W32   = (const float*)d_in[20];
    const float* b32   = (const float*)d_in[21];
    const float* n1g   = (const float*)d_in[22];
    const float* n1b   = (const float*)d_in[23];
    const float* n2g   = (const float*)d_in[24];
    const float* n2b   = (const float*)d_in[25];
    const float* n3g   = (const float*)d_in[26];
    const float* n3b   = (const float*)d_in[27];

    // d_ws: e2 [8 MB] | Wpk [192 KB]
    float*    e2  = (float*)d_ws;
    unsigned* Wpk = (unsigned*)((float*)d_ws + (size_t)BB * EE * DD);
    float*    out = (float*)d_out;   // v2 -> x1 (in place) -> final

    dim3 blk(NTHREADS);
    convert_w_kernel<<<dim3((6 * WPK_U32 + NTHREADS - 1) / NTHREADS), blk, 0, stream>>>(
        W11, W12, W21, W22, W31, W32, Wpk);
    stage1_kernel<<<dim3(2 * BB * EE / ROWS), blk, 0, stream>>>(
        x_e, x_v, emask, nmask, eord, pe1, n1g, n1b, Wpk, b11, b12, e2, out);
    gather_kernel<<<dim3(BB * NN / (NTHREADS / 64)), blk, 0, stream>>>(
        out, nmask, inc, sn, e2);
    node2_kernel<<<dim3(BB * NN / ROWS), blk, 0, stream>>>(
        out, nmask, pe2, biasb, n2g, n2b, n3g, n3b, Wpk, b21, b22, b31, b32, out);
}